// Round 4
// baseline (106.594 us; speedup 1.0000x reference)
//
#include <hip/hip_runtime.h>
#include <hip/hip_bf16.h>

// FirDownsample: y = depthwise FIR(4x4 separable [1,3,3,1]) on x (pad 2),
// out = conv3x3(y, w), stride 2.  x:(16,320,64,64) f32, out:(16,320,32,32) f32.
//
// R4: conv block M128(8oh x 16ow) x N64, wave M64xN32 -> 2x MFMA per barrier,
// half the B (w-fragment) L2 traffic per FLOP vs R3. Same conflict-free 80B-padded
// LDS scheme, same T14 reg-staged prefetch.
//   K1 fir_kernel : x -> y[n][cc=10][65][65][32ci] bf16
//   K2 wt2_kernel : w -> wt2[tap][cc][q][co][8ci] bf16
//   K3 conv_kernel: LDS-staged A, global B, 2 barriers/cc.

typedef short bf16x8_t __attribute__((ext_vector_type(8)));
typedef float f32x4 __attribute__((ext_vector_type(4)));
typedef unsigned int u32x4 __attribute__((ext_vector_type(4)));

#define NI 16
#define CCH 320
#define HW 64
#define HY 65
#define HY2 4225           // 65*65
#define CCSTEP 135200      // 4225*32 shorts per cc-plane

// ---------------- K1: separable FIR, x(f32) -> y bf16 [n][cc][r][c][32] ----------------
__global__ __launch_bounds__(256) void fir_kernel(const float* __restrict__ x,
                                                  const float* __restrict__ fir_k,
                                                  __hip_bfloat16* __restrict__ yt) {
    __shared__ float vlds[8 * 68 * 17];  // [j][cc][ci+pad]
    int bx = blockIdx.x;
    int n   = bx / 180;
    int rr  = bx % 180;
    int r0  = (rr / 20) * 8;
    int ci0 = (rr % 20) * 16;

    float f0 = fir_k[0] + fir_k[1] + fir_k[2] + fir_k[3];
    float f1 = fir_k[4] + fir_k[5] + fir_k[6] + fir_k[7];
    float f2 = fir_k[8] + fir_k[9] + fir_k[10] + fir_k[11];
    float f3 = fir_k[12] + fir_k[13] + fir_k[14] + fir_k[15];

    int tid = threadIdx.x;
    int lane = tid & 63;
    int g = tid >> 6;

    for (int cis = g; cis < 16; cis += 4) {
        int ci = ci0 + cis;
        const float* xb = x + (size_t)(n * CCH + ci) * HW * HW;
        float xr[11];
#pragma unroll
        for (int jr = 0; jr < 11; ++jr) {
            int row = r0 + jr - 2;
            xr[jr] = (row >= 0 && row < HW) ? xb[row * HW + lane] : 0.f;
        }
#pragma unroll
        for (int j = 0; j < 8; ++j) {
            float v = f0 * xr[j] + f1 * xr[j + 1] + f2 * xr[j + 2] + f3 * xr[j + 3];
            vlds[(j * 68 + lane + 2) * 17 + cis] = v;
            if (lane < 2)   vlds[(j * 68 + lane) * 17 + cis] = 0.f;
            if (lane >= 62) vlds[(j * 68 + lane + 4) * 17 + cis] = 0.f;
        }
    }
    __syncthreads();

    int cis = tid & 15;
    int cl  = tid >> 4;
    int ci  = ci0 + cis;
    size_t obase = (size_t)(n * 10 + (ci >> 5)) * HY2 * 32 + (ci & 31);
#pragma unroll
    for (int j = 0; j < 8; ++j) {
        if (r0 + j >= HY) break;
        for (int cb = 0; cb < 5; ++cb) {
            int c = cb * 16 + cl;
            if (c < HY) {
                float yv = f0 * vlds[(j * 68 + c) * 17 + cis]
                         + f1 * vlds[(j * 68 + c + 1) * 17 + cis]
                         + f2 * vlds[(j * 68 + c + 2) * 17 + cis]
                         + f3 * vlds[(j * 68 + c + 3) * 17 + cis];
                yt[obase + (size_t)((r0 + j) * HY + c) * 32] = __float2bfloat16(yv);
            }
        }
    }
}

// ---------------- K2: w (co,ci,3,3) f32 -> wt2[tap][cc][q][co][8] bf16 ----------------
__global__ __launch_bounds__(256) void wt2_kernel(const float* __restrict__ w,
                                                  __hip_bfloat16* __restrict__ wt) {
    int idx = blockIdx.x * 256 + threadIdx.x;
    if (idx < 9 * CCH * CCH) {
        int j  = idx & 7;
        int co = (idx >> 3) % CCH;
        int t2 = idx / 2560;          // tap*40 + cc*4 + q
        int q  = t2 & 3;
        int cc = (t2 >> 2) % 10;
        int tap = t2 / 40;
        int ci = cc * 32 + q * 8 + j;
        wt[idx] = __float2bfloat16(w[(co * CCH + ci) * 9 + tap]);
    }
}

// ---------------- K3: LDS-staged MFMA conv, M128 x N64 ----------------
// grid = (n*5 + cb)*8 + sp ; 4 waves = 2(wm) x 2(wn); wave M64(4oh x 16ow) x N32.
// LDS: 561 positions (17r x 33c) x 32ci, rows padded to 80B -> conflict-free b128.
__global__ __launch_bounds__(256, 2) void conv_kernel(const __hip_bfloat16* __restrict__ yt,
                                                      const __hip_bfloat16* __restrict__ wt2,
                                                      float* __restrict__ out) {
    __shared__ short ylds[2805 * 8];   // 44,880 B ; pos p -> 16B units 5p..5p+3 (+pad)

    int bx = blockIdx.x;
    int sp = bx & 7;
    int t  = bx >> 3;
    int cb = t % 5;
    int n  = t / 5;
    int co0 = cb * 64;
    int oh0 = (sp >> 1) * 8;
    int ow0 = (sp & 1) * 16;

    int tid = threadIdx.x;
    int lane = tid & 63;
    int wid = tid >> 6;
    int wm = wid >> 1, wn = wid & 1;
    int q = lane >> 4, lc = lane & 15;

    const unsigned short* ytu = (const unsigned short*)yt;
    const unsigned short* wtu = (const unsigned short*)wt2;

    // staging source offsets (shorts), cc=0; per-cc add CCSTEP
    int ybase = (n * 10 * HY2 + (2 * oh0) * HY + 2 * ow0) * 32;
    int goff[9];
    bool gv[9];
    int lws[9];
#pragma unroll
    for (int k = 0; k < 9; ++k) {
        int u = k * 256 + tid;
        gv[k] = (u < 2244);
        int uc = gv[k] ? u : 2243;
        int p = uc >> 2, s = uc & 3;
        int pr = p / 33, pc = p - pr * 33;
        goff[k] = ybase + (pr * HY + pc) * 32 + s * 8;
        lws[k] = p * 40 + s * 8;          // LDS short-index (80B row pitch)
    }

    const unsigned short* wbl = wtu + q * 2560 + (size_t)(co0 + wn * 32 + lc) * 8;
    const short* abase = ylds + (8 * wm * 33 + 2 * lc) * 40 + q * 8;

    f32x4 acc[4][2];
#pragma unroll
    for (int i = 0; i < 4; ++i)
#pragma unroll
        for (int j = 0; j < 2; ++j) acc[i][j] = (f32x4){0.f, 0.f, 0.f, 0.f};

    // prologue: prefetch stage regs for cc=0
    u32x4 stg[9];
#pragma unroll
    for (int k = 0; k < 9; ++k)
        if (gv[k]) stg[k] = *(const u32x4*)(ytu + goff[k]);

    for (int cc = 0; cc < 10; ++cc) {
        __syncthreads();                       // (1) prev reads of ylds done
#pragma unroll
        for (int k = 0; k < 9; ++k)
            if (gv[k]) *(u32x4*)(ylds + lws[k]) = stg[k];
        __syncthreads();                       // (2) writes visible (vmem queue empty)

        const unsigned short* wcc = wbl + cc * 10240;
        // B frags for kw=0 (issued first in vmem queue)
        bf16x8_t b0[3][2];
#pragma unroll
        for (int kh = 0; kh < 3; ++kh)
#pragma unroll
            for (int nf = 0; nf < 2; ++nf)
                b0[kh][nf] = *(const bf16x8_t*)(wcc + (kh * 3 + 0) * 102400 + nf * 128);
        // next-tile stage prefetch: in flight across the whole compute phase
        if (cc < 9) {
#pragma unroll
            for (int k = 0; k < 9; ++k)
                if (gv[k]) stg[k] = *(const u32x4*)(ytu + goff[k] + (cc + 1) * CCSTEP);
        }

        bf16x8_t af[10];
        // ---- kw = 0 ----
#pragma unroll
        for (int rl = 0; rl < 10; ++rl)
            af[rl] = *(const bf16x8_t*)(abase + (rl * 33 + 0) * 40);
        bf16x8_t b1[3][2];
#pragma unroll
        for (int kh = 0; kh < 3; ++kh)
#pragma unroll
            for (int nf = 0; nf < 2; ++nf)
                b1[kh][nf] = *(const bf16x8_t*)(wcc + (kh * 3 + 1) * 102400 + nf * 128);
#pragma unroll
        for (int kh = 0; kh < 3; ++kh)
#pragma unroll
            for (int mf = 0; mf < 4; ++mf)
#pragma unroll
                for (int nf = 0; nf < 2; ++nf)
                    acc[mf][nf] = __builtin_amdgcn_mfma_f32_16x16x32_bf16(
                        b0[kh][nf], af[2 * mf + kh], acc[mf][nf], 0, 0, 0);

        // ---- kw = 1 ----
#pragma unroll
        for (int rl = 0; rl < 10; ++rl)
            af[rl] = *(const bf16x8_t*)(abase + (rl * 33 + 1) * 40);
        bf16x8_t b2[3][2];
#pragma unroll
        for (int kh = 0; kh < 3; ++kh)
#pragma unroll
            for (int nf = 0; nf < 2; ++nf)
                b2[kh][nf] = *(const bf16x8_t*)(wcc + (kh * 3 + 2) * 102400 + nf * 128);
#pragma unroll
        for (int kh = 0; kh < 3; ++kh)
#pragma unroll
            for (int mf = 0; mf < 4; ++mf)
#pragma unroll
                for (int nf = 0; nf < 2; ++nf)
                    acc[mf][nf] = __builtin_amdgcn_mfma_f32_16x16x32_bf16(
                        b1[kh][nf], af[2 * mf + kh], acc[mf][nf], 0, 0, 0);

        // ---- kw = 2 ----
#pragma unroll
        for (int rl = 0; rl < 10; ++rl)
            af[rl] = *(const bf16x8_t*)(abase + (rl * 33 + 2) * 40);
#pragma unroll
        for (int kh = 0; kh < 3; ++kh)
#pragma unroll
            for (int mf = 0; mf < 4; ++mf)
#pragma unroll
                for (int nf = 0; nf < 2; ++nf)
                    acc[mf][nf] = __builtin_amdgcn_mfma_f32_16x16x32_bf16(
                        b2[kh][nf], af[2 * mf + kh], acc[mf][nf], 0, 0, 0);
    }

    // epilogue: D[row=co][col=m]; coalesced 64B segments
#pragma unroll
    for (int mf = 0; mf < 4; ++mf) {
        int oh = oh0 + wm * 4 + mf;
        int ow = ow0 + lc;
#pragma unroll
        for (int nf = 0; nf < 2; ++nf) {
#pragma unroll
            for (int rg = 0; rg < 4; ++rg) {
                int co = co0 + wn * 32 + nf * 16 + q * 4 + rg;
                out[((n * CCH + co) * 32 + oh) * 32 + ow] = acc[mf][nf][rg];
            }
        }
    }
}

// ---------------- Fallback: naive direct (correct, slow) ----------------
__global__ __launch_bounds__(256) void naive_kernel(const float* __restrict__ x,
                                                    const float* __restrict__ w,
                                                    const float* __restrict__ fk,
                                                    float* __restrict__ out) {
    int idx = blockIdx.x * 256 + threadIdx.x;
    if (idx >= NI * CCH * 32 * 32) return;
    int ow = idx & 31;
    int oh = (idx >> 5) & 31;
    int co = (idx >> 10) % CCH;
    int n = (idx >> 10) / CCH;
    float f0 = fk[0] + fk[1] + fk[2] + fk[3];
    float f1 = fk[4] + fk[5] + fk[6] + fk[7];
    float f2 = fk[8] + fk[9] + fk[10] + fk[11];
    float f3 = fk[12] + fk[13] + fk[14] + fk[15];
    float fv[4] = {f0, f1, f2, f3};
    float acc = 0.f;
    for (int ci = 0; ci < CCH; ++ci) {
        const float* xb = x + (size_t)(n * CCH + ci) * HW * HW;
        const float* wb = w + (size_t)(co * CCH + ci) * 9;
#pragma unroll
        for (int u = 0; u < 3; ++u) {
            int yr = 2 * oh + u;
#pragma unroll
            for (int v = 0; v < 3; ++v) {
                int yc = 2 * ow + v;
                float s = 0.f;
#pragma unroll
                for (int a = 0; a < 4; ++a) {
                    int xrw = yr - 2 + a;
                    if (xrw < 0 || xrw >= HW) continue;
                    float t = 0.f;
#pragma unroll
                    for (int b = 0; b < 4; ++b) {
                        int xc = yc - 2 + b;
                        if (xc >= 0 && xc < HW) t += fv[b] * xb[xrw * HW + xc];
                    }
                    s += fv[a] * t;
                }
                acc += wb[u * 3 + v] * s;
            }
        }
    }
    out[idx] = acc;
}

extern "C" void kernel_launch(void* const* d_in, const int* in_sizes, int n_in,
                              void* d_out, int out_size, void* d_ws, size_t ws_size,
                              hipStream_t stream) {
    const float* x = (const float*)d_in[0];
    const float* w = (const float*)d_in[1];
    const float* fk = (const float*)d_in[2];
    float* out = (float*)d_out;

    const size_t ybytes = (size_t)NI * 10 * HY2 * 32 * 2;     // 43,264,000
    const size_t wtoff = ybytes;
    const size_t need = wtoff + (size_t)9 * CCH * CCH * 2;    // 45,107,200

    if (ws_size >= need) {
        __hip_bfloat16* yt = (__hip_bfloat16*)d_ws;
        __hip_bfloat16* wt = (__hip_bfloat16*)((char*)d_ws + wtoff);
        fir_kernel<<<16 * 9 * 20, 256, 0, stream>>>(x, fk, yt);
        wt2_kernel<<<(9 * CCH * CCH + 255) / 256, 256, 0, stream>>>(w, wt);
        conv_kernel<<<16 * 5 * 8, 256, 0, stream>>>(yt, wt, out);
    } else {
        naive_kernel<<<(NI * CCH * 32 * 32 + 255) / 256, 256, 0, stream>>>(x, w, fk, out);
    }
}

// Round 5
// 104.033 us; speedup vs baseline: 1.0246x; 1.0246x over previous
//
#include <hip/hip_runtime.h>
#include <hip/hip_bf16.h>

// FirDownsample: y = depthwise FIR(4x4 separable [1,3,3,1]) on x (pad 2),
// out = conv3x3(y, w), stride 2.  x:(16,320,64,64) f32, out:(16,320,32,32) f32.
//
// R5: back to R3 geometry (M64xN64, 2560 blocks) + DOUBLE-BUFFERED LDS with ONE
// barrier per cc (T3 minimum-2-phase): stage loads for cc+1 issued at top of
// compute, ds_write to buf^1 after compute, single __syncthreads per cc.
// fir: 2 ci per thread -> 4B stores (half the store instructions).
//   K1 fir_kernel : x -> y[n][cc=10][65][65][32ci] bf16
//   K2 wt2_kernel : w -> wt2[tap][cc][q][co][8ci] bf16
//   K3 conv_kernel: LDS-staged A (dbuf), global B, 1 barrier/cc.

typedef short bf16x8_t __attribute__((ext_vector_type(8)));
typedef float f32x4 __attribute__((ext_vector_type(4)));
typedef unsigned int u32x4 __attribute__((ext_vector_type(4)));

#define NI 16
#define CCH 320
#define HW 64
#define HY 65
#define HY2 4225           // 65*65
#define CCSTEP 135200      // 4225*32 shorts per cc-plane

// ---------------- K1: separable FIR, x(f32) -> y bf16 [n][cc][r][c][32] ----------------
__global__ __launch_bounds__(256) void fir_kernel(const float* __restrict__ x,
                                                  const float* __restrict__ fir_k,
                                                  __hip_bfloat16* __restrict__ yt) {
    __shared__ float vlds[8 * 68 * 17];  // [j][cc][ci+pad]
    int bx = blockIdx.x;
    int n   = bx / 180;
    int rr  = bx % 180;
    int r0  = (rr / 20) * 8;
    int ci0 = (rr % 20) * 16;

    float f0 = fir_k[0] + fir_k[1] + fir_k[2] + fir_k[3];
    float f1 = fir_k[4] + fir_k[5] + fir_k[6] + fir_k[7];
    float f2 = fir_k[8] + fir_k[9] + fir_k[10] + fir_k[11];
    float f3 = fir_k[12] + fir_k[13] + fir_k[14] + fir_k[15];

    int tid = threadIdx.x;
    int lane = tid & 63;
    int g = tid >> 6;

    for (int cis = g; cis < 16; cis += 4) {
        int ci = ci0 + cis;
        const float* xb = x + (size_t)(n * CCH + ci) * HW * HW;
        float xr[11];
#pragma unroll
        for (int jr = 0; jr < 11; ++jr) {
            int row = r0 + jr - 2;
            xr[jr] = (row >= 0 && row < HW) ? xb[row * HW + lane] : 0.f;
        }
#pragma unroll
        for (int j = 0; j < 8; ++j) {
            float v = f0 * xr[j] + f1 * xr[j + 1] + f2 * xr[j + 2] + f3 * xr[j + 3];
            vlds[(j * 68 + lane + 2) * 17 + cis] = v;
            if (lane < 2)   vlds[(j * 68 + lane) * 17 + cis] = 0.f;
            if (lane >= 62) vlds[(j * 68 + lane + 4) * 17 + cis] = 0.f;
        }
    }
    __syncthreads();

    // horiz pass: 2 adjacent ci per thread -> 4B stores
    int p  = tid & 7;          // ci-pair index
    int cl = tid >> 3;         // 0..31
    int cis0 = 2 * p;
    int ci  = ci0 + cis0;
    size_t obase = (size_t)(n * 10 + (ci >> 5)) * HY2 * 32 + (ci & 31);
    unsigned int* ytp = (unsigned int*)yt;   // 2 bf16 per store
#pragma unroll
    for (int j = 0; j < 8; ++j) {
        if (r0 + j >= HY) break;
#pragma unroll
        for (int cb = 0; cb < 3; ++cb) {
            int c = cb * 32 + cl;
            if (c < HY) {
                int vb = (j * 68 + c) * 17;
                float y0 = f0 * vlds[vb + cis0]      + f1 * vlds[vb + 17 + cis0]
                         + f2 * vlds[vb + 34 + cis0] + f3 * vlds[vb + 51 + cis0];
                float y1 = f0 * vlds[vb + cis0 + 1]      + f1 * vlds[vb + 17 + cis0 + 1]
                         + f2 * vlds[vb + 34 + cis0 + 1] + f3 * vlds[vb + 51 + cis0 + 1];
                unsigned int b0 = (__bfloat16_as_ushort(__float2bfloat16(y0)));
                unsigned int b1 = (__bfloat16_as_ushort(__float2bfloat16(y1)));
                ytp[(obase + (size_t)((r0 + j) * HY + c) * 32) >> 1] = b0 | (b1 << 16);
            }
        }
    }
}

// ---------------- K2: w (co,ci,3,3) f32 -> wt2[tap][cc][q][co][8] bf16 ----------------
__global__ __launch_bounds__(256) void wt2_kernel(const float* __restrict__ w,
                                                  __hip_bfloat16* __restrict__ wt) {
    int idx = blockIdx.x * 256 + threadIdx.x;
    if (idx < 9 * CCH * CCH) {
        int j  = idx & 7;
        int co = (idx >> 3) % CCH;
        int t2 = idx / 2560;          // tap*40 + cc*4 + q
        int q  = t2 & 3;
        int cc = (t2 >> 2) % 10;
        int tap = t2 / 40;
        int ci = cc * 32 + q * 8 + j;
        wt[idx] = __float2bfloat16(w[(co * CCH + ci) * 9 + tap]);
    }
}

// ---------------- K3: dbuf LDS-staged MFMA conv, M64 x N64 ----------------
// grid = (n*5 + cb)*16 + sp ; 4 waves = 2(wm) x 2(wn); wave M32(2oh x 16ow) x N32.
// LDS: 2 x (297 positions x 5 16B-units, 80B row pitch) -> conflict-free b128.
__global__ __launch_bounds__(256, 3) void conv_kernel(const __hip_bfloat16* __restrict__ yt,
                                                      const __hip_bfloat16* __restrict__ wt2,
                                                      float* __restrict__ out) {
    __shared__ short ylds[2][1485 * 8];   // 2 x 23,760 B

    int bx = blockIdx.x;
    int sp = bx & 15;
    int t  = bx >> 4;
    int cb = t % 5;
    int n  = t / 5;
    int co0 = cb * 64;
    int oh0 = (sp >> 1) * 4;
    int ow0 = (sp & 1) * 16;

    int tid = threadIdx.x;
    int lane = tid & 63;
    int wid = tid >> 6;
    int wm = wid >> 1, wn = wid & 1;
    int q = lane >> 4, lc = lane & 15;

    const unsigned short* ytu = (const unsigned short*)yt;
    const unsigned short* wtu = (const unsigned short*)wt2;

    // staging source offsets (shorts), cc=0; per-cc add CCSTEP. Linear LDS write
    // (includes pad unit, written with dup of unit 3 -> never read).
    int ybase = (n * 10 * HY2 + (2 * oh0) * HY + 2 * ow0) * 32;
    int goff[6];
    bool gv[6];
#pragma unroll
    for (int k = 0; k < 6; ++k) {
        int u = k * 256 + tid;
        gv[k] = (u < 1485);
        int uc = gv[k] ? u : 1484;
        int p = uc / 5, s = uc - p * 5;
        if (s == 4) s = 3;                 // pad unit: safe dup, never read
        int pr = p / 33, pc = p - pr * 33;
        goff[k] = ybase + (pr * HY + pc) * 32 + s * 8;
    }

    const unsigned short* wbl = wtu + q * 2560 + (size_t)(co0 + wn * 32 + lc) * 8;
    const int aoff = (4 * wm * 33 + 2 * lc) * 40 + q * 8;

    f32x4 acc[2][2];
#pragma unroll
    for (int i = 0; i < 2; ++i)
#pragma unroll
        for (int j = 0; j < 2; ++j) acc[i][j] = (f32x4){0.f, 0.f, 0.f, 0.f};

    // prologue: stage cc=0 into buf0
    u32x4 stg[6];
#pragma unroll
    for (int k = 0; k < 6; ++k)
        if (gv[k]) stg[k] = *(const u32x4*)(ytu + goff[k]);
#pragma unroll
    for (int k = 0; k < 6; ++k)
        if (gv[k]) *(u32x4*)(&ylds[0][0] + (k * 256 + tid) * 8) = stg[k];
    __syncthreads();

    for (int cc = 0; cc < 10; ++cc) {
        const short* buf = &ylds[cc & 1][0];
        short* nbuf = &ylds[(cc & 1) ^ 1][0];
        const unsigned short* wcc = wbl + cc * 10240;

        // B frags for kw=0 (first in vmem queue)
        bf16x8_t b0[3][2];
#pragma unroll
        for (int kh = 0; kh < 3; ++kh)
#pragma unroll
            for (int nf = 0; nf < 2; ++nf)
                b0[kh][nf] = *(const bf16x8_t*)(wcc + (kh * 3 + 0) * 102400 + nf * 128);
        // next-cc stage prefetch: in flight across the whole compute phase
        if (cc < 9) {
#pragma unroll
            for (int k = 0; k < 6; ++k)
                if (gv[k]) stg[k] = *(const u32x4*)(ytu + goff[k] + (cc + 1) * CCSTEP);
        }

        bf16x8_t af[5];
        // ---- kw = 0 ----
#pragma unroll
        for (int rl = 0; rl < 5; ++rl)
            af[rl] = *(const bf16x8_t*)(buf + aoff + (rl * 33 + 0) * 40);
        bf16x8_t b1[3][2];
#pragma unroll
        for (int kh = 0; kh < 3; ++kh)
#pragma unroll
            for (int nf = 0; nf < 2; ++nf)
                b1[kh][nf] = *(const bf16x8_t*)(wcc + (kh * 3 + 1) * 102400 + nf * 128);
#pragma unroll
        for (int kh = 0; kh < 3; ++kh)
#pragma unroll
            for (int mf = 0; mf < 2; ++mf)
#pragma unroll
                for (int nf = 0; nf < 2; ++nf)
                    acc[mf][nf] = __builtin_amdgcn_mfma_f32_16x16x32_bf16(
                        b0[kh][nf], af[2 * mf + kh], acc[mf][nf], 0, 0, 0);

        // ---- kw = 1 ----
#pragma unroll
        for (int rl = 0; rl < 5; ++rl)
            af[rl] = *(const bf16x8_t*)(buf + aoff + (rl * 33 + 1) * 40);
        bf16x8_t b2[3][2];
#pragma unroll
        for (int kh = 0; kh < 3; ++kh)
#pragma unroll
            for (int nf = 0; nf < 2; ++nf)
                b2[kh][nf] = *(const bf16x8_t*)(wcc + (kh * 3 + 2) * 102400 + nf * 128);
#pragma unroll
        for (int kh = 0; kh < 3; ++kh)
#pragma unroll
            for (int mf = 0; mf < 2; ++mf)
#pragma unroll
                for (int nf = 0; nf < 2; ++nf)
                    acc[mf][nf] = __builtin_amdgcn_mfma_f32_16x16x32_bf16(
                        b1[kh][nf], af[2 * mf + kh], acc[mf][nf], 0, 0, 0);

        // ---- kw = 2 ----
#pragma unroll
        for (int rl = 0; rl < 5; ++rl)
            af[rl] = *(const bf16x8_t*)(buf + aoff + (rl * 33 + 2) * 40);
#pragma unroll
        for (int kh = 0; kh < 3; ++kh)
#pragma unroll
            for (int mf = 0; mf < 2; ++mf)
#pragma unroll
                for (int nf = 0; nf < 2; ++nf)
                    acc[mf][nf] = __builtin_amdgcn_mfma_f32_16x16x32_bf16(
                        b2[kh][nf], af[2 * mf + kh], acc[mf][nf], 0, 0, 0);

        // write next tile to the other buffer (prev barrier guarantees it's free)
        if (cc < 9) {
#pragma unroll
            for (int k = 0; k < 6; ++k)
                if (gv[k]) *(u32x4*)(nbuf + (k * 256 + tid) * 8) = stg[k];
        }
        __syncthreads();        // one barrier per cc
    }

    // epilogue: D[row=co][col=m]; coalesced 64B segments
#pragma unroll
    for (int mf = 0; mf < 2; ++mf) {
        int oh = oh0 + wm * 2 + mf;
        int ow = ow0 + lc;
#pragma unroll
        for (int nf = 0; nf < 2; ++nf) {
#pragma unroll
            for (int rg = 0; rg < 4; ++rg) {
                int co = co0 + wn * 32 + nf * 16 + q * 4 + rg;
                out[((n * CCH + co) * 32 + oh) * 32 + ow] = acc[mf][nf][rg];
            }
        }
    }
}

// ---------------- Fallback: naive direct (correct, slow) ----------------
__global__ __launch_bounds__(256) void naive_kernel(const float* __restrict__ x,
                                                    const float* __restrict__ w,
                                                    const float* __restrict__ fk,
                                                    float* __restrict__ out) {
    int idx = blockIdx.x * 256 + threadIdx.x;
    if (idx >= NI * CCH * 32 * 32) return;
    int ow = idx & 31;
    int oh = (idx >> 5) & 31;
    int co = (idx >> 10) % CCH;
    int n = (idx >> 10) / CCH;
    float f0 = fk[0] + fk[1] + fk[2] + fk[3];
    float f1 = fk[4] + fk[5] + fk[6] + fk[7];
    float f2 = fk[8] + fk[9] + fk[10] + fk[11];
    float f3 = fk[12] + fk[13] + fk[14] + fk[15];
    float fv[4] = {f0, f1, f2, f3};
    float acc = 0.f;
    for (int ci = 0; ci < CCH; ++ci) {
        const float* xb = x + (size_t)(n * CCH + ci) * HW * HW;
        const float* wb = w + (size_t)(co * CCH + ci) * 9;
#pragma unroll
        for (int u = 0; u < 3; ++u) {
            int yr = 2 * oh + u;
#pragma unroll
            for (int v = 0; v < 3; ++v) {
                int yc = 2 * ow + v;
                float s = 0.f;
#pragma unroll
                for (int a = 0; a < 4; ++a) {
                    int xrw = yr - 2 + a;
                    if (xrw < 0 || xrw >= HW) continue;
                    float t = 0.f;
#pragma unroll
                    for (int b = 0; b < 4; ++b) {
                        int xc = yc - 2 + b;
                        if (xc >= 0 && xc < HW) t += fv[b] * xb[xrw * HW + xc];
                    }
                    s += fv[a] * t;
                }
                acc += wb[u * 3 + v] * s;
            }
        }
    }
    out[idx] = acc;
}

extern "C" void kernel_launch(void* const* d_in, const int* in_sizes, int n_in,
                              void* d_out, int out_size, void* d_ws, size_t ws_size,
                              hipStream_t stream) {
    const float* x = (const float*)d_in[0];
    const float* w = (const float*)d_in[1];
    const float* fk = (const float*)d_in[2];
    float* out = (float*)d_out;

    const size_t ybytes = (size_t)NI * 10 * HY2 * 32 * 2;     // 43,264,000
    const size_t wtoff = ybytes;
    const size_t need = wtoff + (size_t)9 * CCH * CCH * 2;    // 45,107,200

    if (ws_size >= need) {
        __hip_bfloat16* yt = (__hip_bfloat16*)d_ws;
        __hip_bfloat16* wt = (__hip_bfloat16*)((char*)d_ws + wtoff);
        fir_kernel<<<16 * 9 * 20, 256, 0, stream>>>(x, fk, yt);
        wt2_kernel<<<(9 * CCH * CCH + 255) / 256, 256, 0, stream>>>(w, wt);
        conv_kernel<<<16 * 5 * 16, 256, 0, stream>>>(yt, wt, out);
    } else {
        naive_kernel<<<(NI * CCH * 32 * 32 + 255) / 256, 256, 0, stream>>>(x, w, fk, out);
    }
}

// Round 6
// 79.729 us; speedup vs baseline: 1.3370x; 1.3048x over previous
//
#include <hip/hip_runtime.h>
#include <hip/hip_bf16.h>

// FirDownsample: y = depthwise FIR(4x4 separable [1,3,3,1]) on x (pad 2),
// out = conv3x3(y, w), stride 2.  x:(16,320,64,64) f32, out:(16,320,32,32) f32.
//
// R6: conv re-tiled wave=M64xN16 (no B duplication in block: 36 KB B/cc),
// B(cc+1) fully double-buffered in registers (no load-use stalls),
// A staged global->LDS via __builtin_amdgcn_global_load_lds (width 16),
// single barrier per cc. Predicted bound: LDS read throughput.
//   K1 fir_kernel : x -> y[n][cc=10][65][65][32ci] bf16
//   K2 wt2_kernel : w -> wt2[tap][cc][q][co][8ci] bf16
//   K3 conv_kernel: M64xN64 block, 4 waves M64xN16.

typedef short bf16x8_t __attribute__((ext_vector_type(8)));
typedef float f32x4 __attribute__((ext_vector_type(4)));
typedef __attribute__((address_space(1))) const unsigned int* as1_u32p;
typedef __attribute__((address_space(3))) unsigned int* as3_u32p;

#define NI 16
#define CCH 320
#define HW 64
#define HY 65
#define HY2 4225           // 65*65
#define CCSTEP 135200      // 4225*32 shorts per cc-plane

// ---------------- K1: separable FIR, x(f32) -> y bf16 [n][cc][r][c][32] ----------------
__global__ __launch_bounds__(256) void fir_kernel(const float* __restrict__ x,
                                                  const float* __restrict__ fir_k,
                                                  __hip_bfloat16* __restrict__ yt) {
    __shared__ float vlds[8 * 68 * 17];  // [j][cc][ci+pad]
    int bx = blockIdx.x;
    int n   = bx / 180;
    int rr  = bx % 180;
    int r0  = (rr / 20) * 8;
    int ci0 = (rr % 20) * 16;

    float f0 = fir_k[0] + fir_k[1] + fir_k[2] + fir_k[3];
    float f1 = fir_k[4] + fir_k[5] + fir_k[6] + fir_k[7];
    float f2 = fir_k[8] + fir_k[9] + fir_k[10] + fir_k[11];
    float f3 = fir_k[12] + fir_k[13] + fir_k[14] + fir_k[15];

    int tid = threadIdx.x;
    int lane = tid & 63;
    int g = tid >> 6;

    for (int cis = g; cis < 16; cis += 4) {
        int ci = ci0 + cis;
        const float* xb = x + (size_t)(n * CCH + ci) * HW * HW;
        float xr[11];
#pragma unroll
        for (int jr = 0; jr < 11; ++jr) {
            int row = r0 + jr - 2;
            xr[jr] = (row >= 0 && row < HW) ? xb[row * HW + lane] : 0.f;
        }
#pragma unroll
        for (int j = 0; j < 8; ++j) {
            float v = f0 * xr[j] + f1 * xr[j + 1] + f2 * xr[j + 2] + f3 * xr[j + 3];
            vlds[(j * 68 + lane + 2) * 17 + cis] = v;
            if (lane < 2)   vlds[(j * 68 + lane) * 17 + cis] = 0.f;
            if (lane >= 62) vlds[(j * 68 + lane + 4) * 17 + cis] = 0.f;
        }
    }
    __syncthreads();

    // horiz pass: 2 adjacent ci per thread -> 4B stores
    int p  = tid & 7;          // ci-pair index
    int cl = tid >> 3;         // 0..31
    int cis0 = 2 * p;
    int ci  = ci0 + cis0;
    size_t obase = (size_t)(n * 10 + (ci >> 5)) * HY2 * 32 + (ci & 31);
    unsigned int* ytp = (unsigned int*)yt;   // 2 bf16 per store
#pragma unroll
    for (int j = 0; j < 8; ++j) {
        if (r0 + j >= HY) break;
#pragma unroll
        for (int cb = 0; cb < 3; ++cb) {
            int c = cb * 32 + cl;
            if (c < HY) {
                int vb = (j * 68 + c) * 17;
                float y0 = f0 * vlds[vb + cis0]      + f1 * vlds[vb + 17 + cis0]
                         + f2 * vlds[vb + 34 + cis0] + f3 * vlds[vb + 51 + cis0];
                float y1 = f0 * vlds[vb + cis0 + 1]      + f1 * vlds[vb + 17 + cis0 + 1]
                         + f2 * vlds[vb + 34 + cis0 + 1] + f3 * vlds[vb + 51 + cis0 + 1];
                unsigned int b0 = (__bfloat16_as_ushort(__float2bfloat16(y0)));
                unsigned int b1 = (__bfloat16_as_ushort(__float2bfloat16(y1)));
                ytp[(obase + (size_t)((r0 + j) * HY + c) * 32) >> 1] = b0 | (b1 << 16);
            }
        }
    }
}

// ---------------- K2: w (co,ci,3,3) f32 -> wt2[tap][cc][q][co][8] bf16 ----------------
__global__ __launch_bounds__(256) void wt2_kernel(const float* __restrict__ w,
                                                  __hip_bfloat16* __restrict__ wt) {
    int idx = blockIdx.x * 256 + threadIdx.x;
    if (idx < 9 * CCH * CCH) {
        int j  = idx & 7;
        int co = (idx >> 3) % CCH;
        int t2 = idx / 2560;          // tap*40 + cc*4 + q
        int q  = t2 & 3;
        int cc = (t2 >> 2) % 10;
        int tap = t2 / 40;
        int ci = cc * 32 + q * 8 + j;
        wt[idx] = __float2bfloat16(w[(co * CCH + ci) * 9 + tap]);
    }
}

// ---------------- K3: MFMA conv, M64 x N64, waves M64xN16, B reg-dbuf ----------------
// grid = (n*5 + cb)*16 + sp ; wave wid owns co chunk wid*16.
// LDS: dbuf of 1536 16B-units; pos p = units 5p..5p+3 (+1 pad) -> 80B row pitch,
// conflict-free b128 reads (verified 0 conflicts in R3/R5).
__global__ __launch_bounds__(256, 3) void conv_kernel(const __hip_bfloat16* __restrict__ yt,
                                                      const __hip_bfloat16* __restrict__ wt2,
                                                      float* __restrict__ out) {
    __shared__ short ylds[2][1536 * 8];   // 2 x 24,576 B

    int bx = blockIdx.x;
    int sp = bx & 15;
    int t  = bx >> 4;
    int cb = t % 5;
    int n  = t / 5;
    int co0 = cb * 64;
    int oh0 = (sp >> 1) * 4;
    int ow0 = (sp & 1) * 16;

    int tid = threadIdx.x;
    int lane = tid & 63;
    int wid = tid >> 6;
    int q = lane >> 4, lc = lane & 15;

    const unsigned short* ytu = (const unsigned short*)yt;
    const unsigned short* wtu = (const unsigned short*)wt2;

    // per-lane global source offsets (shorts) for staging units, cc=0
    int ybase = (n * 10 * HY2 + (2 * oh0) * HY + 2 * ow0) * 32;
    int goff[6];
#pragma unroll
    for (int k = 0; k < 6; ++k) {
        int u = k * 256 + tid;
        int uc = (u < 1485) ? u : 1484;    // tail: safe dup, lands in pad units
        int p = uc / 5, s = uc - p * 5;
        if (s == 4) s = 3;                 // row-pad unit: dup of unit 3, never read
        int pr = p / 33, pc = p - pr * 33;
        goff[k] = ybase + (pr * HY + pc) * 32 + s * 8;
    }

    const unsigned short* wbl = wtu + q * 2560 + (size_t)(co0 + wid * 16 + lc) * 8;
    const int aoff = (2 * lc) * 40 + q * 8;   // short-index within buffer

    f32x4 acc[4];
#pragma unroll
    for (int i = 0; i < 4; ++i) acc[i] = (f32x4){0.f, 0.f, 0.f, 0.f};

    bf16x8_t bfr[2][9];

    // wave-uniform LDS unit base for stage issue k: (k*256 + wid*64) units
#define GLDS(buf, K, ccidx)                                                            \
    __builtin_amdgcn_global_load_lds(                                                  \
        (as1_u32p)(ytu + goff[K] + (ccidx) * CCSTEP),                                  \
        (as3_u32p)(&ylds[buf][(size_t)((K) * 256 + wid * 64) * 8]), 16, 0, 0)

    // prologue: stage A(0) -> buf0, load B(0) -> bfr[0]
#pragma unroll
    for (int k = 0; k < 6; ++k) GLDS(0, k, 0);
#pragma unroll
    for (int kk = 0; kk < 9; ++kk)
        bfr[0][kk] = *(const bf16x8_t*)(wbl + kk * 102400);
    __syncthreads();

    auto compute = [&](const short* buf, const bf16x8_t* b) {
#pragma unroll
        for (int kw = 0; kw < 3; ++kw) {
            bf16x8_t af[9];
#pragma unroll
            for (int r = 0; r < 9; ++r)
                af[r] = *(const bf16x8_t*)(buf + aoff + (r * 33 + kw) * 40);
#pragma unroll
            for (int kh = 0; kh < 3; ++kh)
#pragma unroll
                for (int mf = 0; mf < 4; ++mf)
                    acc[mf] = __builtin_amdgcn_mfma_f32_16x16x32_bf16(
                        b[kh * 3 + kw], af[2 * mf + kh], acc[mf], 0, 0, 0);
        }
    };

    for (int tt = 0; tt < 5; ++tt) {
        int cc0 = 2 * tt, cc1 = 2 * tt + 1;
        // ---- even cc: compute from buf0/bfr[0]; prefetch cc0+1 -> buf1/bfr[1]
        {
#pragma unroll
            for (int k = 0; k < 6; ++k) GLDS(1, k, cc0 + 1);
            const unsigned short* wnx = wbl + (cc0 + 1) * 10240;
#pragma unroll
            for (int kk = 0; kk < 9; ++kk)
                bfr[1][kk] = *(const bf16x8_t*)(wnx + kk * 102400);
            compute(&ylds[0][0], bfr[0]);
            __syncthreads();   // drains vmcnt -> A(cc0+1) in LDS, bfr[1] ready
        }
        // ---- odd cc: compute from buf1/bfr[1]; prefetch cc1+1 -> buf0/bfr[0]
        {
            if (cc1 < 9) {
#pragma unroll
                for (int k = 0; k < 6; ++k) GLDS(0, k, cc1 + 1);
                const unsigned short* wnx = wbl + (cc1 + 1) * 10240;
#pragma unroll
                for (int kk = 0; kk < 9; ++kk)
                    bfr[0][kk] = *(const bf16x8_t*)(wnx + kk * 102400);
            }
            compute(&ylds[1][0], bfr[1]);
            if (cc1 < 9) __syncthreads();
        }
    }
#undef GLDS

    // epilogue: D[row=co][col=m]; coalesced 64B segments
#pragma unroll
    for (int mf = 0; mf < 4; ++mf) {
        int oh = oh0 + mf;
        int ow = ow0 + lc;
#pragma unroll
        for (int rg = 0; rg < 4; ++rg) {
            int co = co0 + wid * 16 + q * 4 + rg;
            out[((n * CCH + co) * 32 + oh) * 32 + ow] = acc[mf][rg];
        }
    }
}

// ---------------- Fallback: naive direct (correct, slow) ----------------
__global__ __launch_bounds__(256) void naive_kernel(const float* __restrict__ x,
                                                    const float* __restrict__ w,
                                                    const float* __restrict__ fk,
                                                    float* __restrict__ out) {
    int idx = blockIdx.x * 256 + threadIdx.x;
    if (idx >= NI * CCH * 32 * 32) return;
    int ow = idx & 31;
    int oh = (idx >> 5) & 31;
    int co = (idx >> 10) % CCH;
    int n = (idx >> 10) / CCH;
    float f0 = fk[0] + fk[1] + fk[2] + fk[3];
    float f1 = fk[4] + fk[5] + fk[6] + fk[7];
    float f2 = fk[8] + fk[9] + fk[10] + fk[11];
    float f3 = fk[12] + fk[13] + fk[14] + fk[15];
    float fv[4] = {f0, f1, f2, f3};
    float acc = 0.f;
    for (int ci = 0; ci < CCH; ++ci) {
        const float* xb = x + (size_t)(n * CCH + ci) * HW * HW;
        const float* wb = w + (size_t)(co * CCH + ci) * 9;
#pragma unroll
        for (int u = 0; u < 3; ++u) {
            int yr = 2 * oh + u;
#pragma unroll
            for (int v = 0; v < 3; ++v) {
                int yc = 2 * ow + v;
                float s = 0.f;
#pragma unroll
                for (int a = 0; a < 4; ++a) {
                    int xrw = yr - 2 + a;
                    if (xrw < 0 || xrw >= HW) continue;
                    float t = 0.f;
#pragma unroll
                    for (int b = 0; b < 4; ++b) {
                        int xc = yc - 2 + b;
                        if (xc >= 0 && xc < HW) t += fv[b] * xb[xrw * HW + xc];
                    }
                    s += fv[a] * t;
                }
                acc += wb[u * 3 + v] * s;
            }
        }
    }
    out[idx] = acc;
}

extern "C" void kernel_launch(void* const* d_in, const int* in_sizes, int n_in,
                              void* d_out, int out_size, void* d_ws, size_t ws_size,
                              hipStream_t stream) {
    const float* x = (const float*)d_in[0];
    const float* w = (const float*)d_in[1];
    const float* fk = (const float*)d_in[2];
    float* out = (float*)d_out;

    const size_t ybytes = (size_t)NI * 10 * HY2 * 32 * 2;     // 43,264,000
    const size_t wtoff = ybytes;
    const size_t need = wtoff + (size_t)9 * CCH * CCH * 2;    // 45,107,200

    if (ws_size >= need) {
        __hip_bfloat16* yt = (__hip_bfloat16*)d_ws;
        __hip_bfloat16* wt = (__hip_bfloat16*)((char*)d_ws + wtoff);
        fir_kernel<<<16 * 9 * 20, 256, 0, stream>>>(x, fk, yt);
        wt2_kernel<<<(9 * CCH * CCH + 255) / 256, 256, 0, stream>>>(w, wt);
        conv_kernel<<<16 * 5 * 16, 256, 0, stream>>>(yt, wt, out);
    } else {
        naive_kernel<<<(NI * CCH * 32 * 32 + 255) / 256, 256, 0, stream>>>(x, w, fk, out);
    }
}

// Round 7
// 78.934 us; speedup vs baseline: 1.3504x; 1.0101x over previous
//
#include <hip/hip_runtime.h>
#include <hip/hip_bf16.h>

// FirDownsample: y = depthwise FIR(4x4 separable [1,3,3,1]) on x (pad 2),
// out = conv3x3(y, w), stride 2.  x:(16,320,64,64) f32, out:(16,320,32,32) f32.
//
// R7: fir rewritten: vert LDS transposed [j][ci][cc] (conflict-free), horiz pass
// writes full ci-octets as b128 (coalesced 1KB/wave-instr). y layout permuted to
// octet-major [n][qg=40][65][65][8ci]; conv only changes its staging source
// offsets (global side of global_load_lds is per-lane).
//   K1 fir_kernel : x -> y[n][qg][r][c][8ci] bf16
//   K2 wt2_kernel : w -> wt2[tap][cc][q][co][8ci] bf16
//   K3 conv_kernel: M64xN64 block, 4 waves M64xN16, B reg-dbuf, A via global_load_lds.

typedef short bf16x8_t __attribute__((ext_vector_type(8)));
typedef float f32x4 __attribute__((ext_vector_type(4)));
typedef unsigned int u32x4 __attribute__((ext_vector_type(4)));
typedef __attribute__((address_space(1))) const unsigned int* as1_u32p;
typedef __attribute__((address_space(3))) unsigned int* as3_u32p;

#define NI 16
#define CCH 320
#define HW 64
#define HY 65
#define HY2 4225           // 65*65
#define CCSTEP 135200      // 4*4225*8 shorts per cc (4 octets)

// ---------------- K1: separable FIR, x(f32) -> y bf16 [n][qg=40][r][c][8ci] ----------------
// block = (n, row-band of 8, 16-ci group). vert pass -> LDS [j][ci16][69] f32,
// horiz pass: thread owns (c, ci-octet) -> 16B stores, 64 lanes contiguous.
__global__ __launch_bounds__(256) void fir_kernel(const float* __restrict__ x,
                                                  const float* __restrict__ fir_k,
                                                  __hip_bfloat16* __restrict__ yt) {
    __shared__ float vlds[8 * 16 * 69];  // [j][ci16][cc69] : 35,328 B
    int bx = blockIdx.x;
    int n   = bx / 180;
    int rr  = bx % 180;
    int r0  = (rr / 20) * 8;
    int ci0 = (rr % 20) * 16;

    float f0 = fir_k[0] + fir_k[1] + fir_k[2] + fir_k[3];
    float f1 = fir_k[4] + fir_k[5] + fir_k[6] + fir_k[7];
    float f2 = fir_k[8] + fir_k[9] + fir_k[10] + fir_k[11];
    float f3 = fir_k[12] + fir_k[13] + fir_k[14] + fir_k[15];

    int tid = threadIdx.x;
    int lane = tid & 63;   // = w (vert), = c (horiz)
    int g = tid >> 6;      // wave id

    // vertical pass: vert[j][ci][w+2] = sum_a f[a] * x[r0+j-2+a][w]
    for (int cis = g; cis < 16; cis += 4) {
        int ci = ci0 + cis;
        const float* xb = x + (size_t)(n * CCH + ci) * HW * HW;
        float xr[11];
#pragma unroll
        for (int jr = 0; jr < 11; ++jr) {
            int row = r0 + jr - 2;
            xr[jr] = (row >= 0 && row < HW) ? xb[row * HW + lane] : 0.f;
        }
#pragma unroll
        for (int j = 0; j < 8; ++j) {
            float v = f0 * xr[j] + f1 * xr[j + 1] + f2 * xr[j + 2] + f3 * xr[j + 3];
            float* vrow = vlds + (j * 16 + cis) * 69;
            vrow[lane + 2] = v;                       // cc = w+2 (2..65)
            if (lane < 2)   vrow[lane] = 0.f;         // cc 0,1
            if (lane >= 62) vrow[lane + 4] = 0.f;     // cc 66,67
        }
    }
    __syncthreads();

    // horizontal pass: slot = (j, oct); wave-uniform slot, c = lane (+ lane63 does c=64)
    unsigned short* yu = (unsigned short*)yt;
#pragma unroll
    for (int i = 0; i < 4; ++i) {
        int slot = 4 * i + g;            // 0..15
        int j = slot >> 1, oct = slot & 1;
        int r = r0 + j;
        if (r >= HY) continue;
        int qg = (rr % 20) * 2 + oct;    // global ci-octet 0..39
        size_t obase = ((size_t)(n * 40 + qg) * HY2 + (size_t)r * HY) * 8;
        const float* vb = vlds + (j * 16 + oct * 8) * 69;
        int nc = (lane == 63) ? 2 : 1;
        for (int e = 0; e < nc; ++e) {
            int c = lane + e;            // 0..64
            float a[8];
#pragma unroll
            for (int u = 0; u < 8; ++u) {
                const float* vr = vb + u * 69 + c;
                a[u] = f0 * vr[0] + f1 * vr[1] + f2 * vr[2] + f3 * vr[3];
            }
            unsigned int wd[4];
#pragma unroll
            for (int h = 0; h < 4; ++h) {
                unsigned int lo = __bfloat16_as_ushort(__float2bfloat16(a[2 * h]));
                unsigned int hi = __bfloat16_as_ushort(__float2bfloat16(a[2 * h + 1]));
                wd[h] = lo | (hi << 16);
            }
            *(u32x4*)(yu + obase + (size_t)c * 8) = (u32x4){wd[0], wd[1], wd[2], wd[3]};
        }
    }
}

// ---------------- K2: w (co,ci,3,3) f32 -> wt2[tap][cc][q][co][8] bf16 ----------------
__global__ __launch_bounds__(256) void wt2_kernel(const float* __restrict__ w,
                                                  __hip_bfloat16* __restrict__ wt) {
    int idx = blockIdx.x * 256 + threadIdx.x;
    if (idx < 9 * CCH * CCH) {
        int j  = idx & 7;
        int co = (idx >> 3) % CCH;
        int t2 = idx / 2560;          // tap*40 + cc*4 + q
        int q  = t2 & 3;
        int cc = (t2 >> 2) % 10;
        int tap = t2 / 40;
        int ci = cc * 32 + q * 8 + j;
        wt[idx] = __float2bfloat16(w[(co * CCH + ci) * 9 + tap]);
    }
}

// ---------------- K3: MFMA conv, M64 x N64, waves M64xN16, B reg-dbuf ----------------
// grid = (n*5 + cb)*16 + sp ; wave wid owns co chunk wid*16.
// LDS: dbuf of 1536 16B-units; pos p = units 5p..5p+3 (+1 pad) -> 80B row pitch,
// conflict-free b128 reads. A staged via global_load_lds width 16.
__global__ __launch_bounds__(256, 3) void conv_kernel(const __hip_bfloat16* __restrict__ yt,
                                                      const __hip_bfloat16* __restrict__ wt2,
                                                      float* __restrict__ out) {
    __shared__ short ylds[2][1536 * 8];   // 2 x 24,576 B

    int bx = blockIdx.x;
    int sp = bx & 15;
    int t  = bx >> 4;
    int cb = t % 5;
    int n  = t / 5;
    int co0 = cb * 64;
    int oh0 = (sp >> 1) * 4;
    int ow0 = (sp & 1) * 16;

    int tid = threadIdx.x;
    int lane = tid & 63;
    int wid = tid >> 6;
    int q = lane >> 4, lc = lane & 15;

    const unsigned short* ytu = (const unsigned short*)yt;
    const unsigned short* wtu = (const unsigned short*)wt2;

    // per-lane global source offsets (shorts) for staging units, cc=0.
    // y layout [n][cc][s=4][r][c][8]: off = ((n*40 + cc*4 + s)*HY2 + r*HY + c)*8
    int ybase = n * 40 * HY2 * 8 + ((2 * oh0) * HY + 2 * ow0) * 8;
    int goff[6];
#pragma unroll
    for (int k = 0; k < 6; ++k) {
        int u = k * 256 + tid;
        int uc = (u < 1485) ? u : 1484;    // tail: safe dup, lands in pad units
        int p = uc / 5, s = uc - p * 5;
        if (s == 4) s = 3;                 // row-pad unit: dup of unit 3, never read
        int pr = p / 33, pc = p - pr * 33;
        goff[k] = ybase + (s * HY2 + pr * HY + pc) * 8;
    }

    const unsigned short* wbl = wtu + q * 2560 + (size_t)(co0 + wid * 16 + lc) * 8;
    const int aoff = (2 * lc) * 40 + q * 8;   // short-index within buffer

    f32x4 acc[4];
#pragma unroll
    for (int i = 0; i < 4; ++i) acc[i] = (f32x4){0.f, 0.f, 0.f, 0.f};

    bf16x8_t bfr[2][9];

    // wave-uniform LDS unit base for stage issue k: (k*256 + wid*64) units
#define GLDS(buf, K, ccidx)                                                            \
    __builtin_amdgcn_global_load_lds(                                                  \
        (as1_u32p)(ytu + goff[K] + (ccidx) * CCSTEP),                                  \
        (as3_u32p)(&ylds[buf][(size_t)((K) * 256 + wid * 64) * 8]), 16, 0, 0)

    // prologue: stage A(0) -> buf0, load B(0) -> bfr[0]
#pragma unroll
    for (int k = 0; k < 6; ++k) GLDS(0, k, 0);
#pragma unroll
    for (int kk = 0; kk < 9; ++kk)
        bfr[0][kk] = *(const bf16x8_t*)(wbl + kk * 102400);
    __syncthreads();

    auto compute = [&](const short* buf, const bf16x8_t* b) {
#pragma unroll
        for (int kw = 0; kw < 3; ++kw) {
            bf16x8_t af[9];
#pragma unroll
            for (int r = 0; r < 9; ++r)
                af[r] = *(const bf16x8_t*)(buf + aoff + (r * 33 + kw) * 40);
#pragma unroll
            for (int kh = 0; kh < 3; ++kh)
#pragma unroll
                for (int mf = 0; mf < 4; ++mf)
                    acc[mf] = __builtin_amdgcn_mfma_f32_16x16x32_bf16(
                        b[kh * 3 + kw], af[2 * mf + kh], acc[mf], 0, 0, 0);
        }
    };

    for (int tt = 0; tt < 5; ++tt) {
        int cc0 = 2 * tt, cc1 = 2 * tt + 1;
        // ---- even cc: compute from buf0/bfr[0]; prefetch cc0+1 -> buf1/bfr[1]
        {
#pragma unroll
            for (int k = 0; k < 6; ++k) GLDS(1, k, cc0 + 1);
            const unsigned short* wnx = wbl + (cc0 + 1) * 10240;
#pragma unroll
            for (int kk = 0; kk < 9; ++kk)
                bfr[1][kk] = *(const bf16x8_t*)(wnx + kk * 102400);
            compute(&ylds[0][0], bfr[0]);
            __syncthreads();   // drains vmcnt -> A(cc0+1) in LDS, bfr[1] ready
        }
        // ---- odd cc: compute from buf1/bfr[1]; prefetch cc1+1 -> buf0/bfr[0]
        {
            if (cc1 < 9) {
#pragma unroll
                for (int k = 0; k < 6; ++k) GLDS(0, k, cc1 + 1);
                const unsigned short* wnx = wbl + (cc1 + 1) * 10240;
#pragma unroll
                for (int kk = 0; kk < 9; ++kk)
                    bfr[0][kk] = *(const bf16x8_t*)(wnx + kk * 102400);
            }
            compute(&ylds[1][0], bfr[1]);
            if (cc1 < 9) __syncthreads();
        }
    }
#undef GLDS

    // epilogue: D[row=co][col=m]; coalesced 64B segments
#pragma unroll
    for (int mf = 0; mf < 4; ++mf) {
        int oh = oh0 + mf;
        int ow = ow0 + lc;
#pragma unroll
        for (int rg = 0; rg < 4; ++rg) {
            int co = co0 + wid * 16 + q * 4 + rg;
            out[((n * CCH + co) * 32 + oh) * 32 + ow] = acc[mf][rg];
        }
    }
}

// ---------------- Fallback: naive direct (correct, slow) ----------------
__global__ __launch_bounds__(256) void naive_kernel(const float* __restrict__ x,
                                                    const float* __restrict__ w,
                                                    const float* __restrict__ fk,
                                                    float* __restrict__ out) {
    int idx = blockIdx.x * 256 + threadIdx.x;
    if (idx >= NI * CCH * 32 * 32) return;
    int ow = idx & 31;
    int oh = (idx >> 5) & 31;
    int co = (idx >> 10) % CCH;
    int n = (idx >> 10) / CCH;
    float f0 = fk[0] + fk[1] + fk[2] + fk[3];
    float f1 = fk[4] + fk[5] + fk[6] + fk[7];
    float f2 = fk[8] + fk[9] + fk[10] + fk[11];
    float f3 = fk[12] + fk[13] + fk[14] + fk[15];
    float fv[4] = {f0, f1, f2, f3};
    float acc = 0.f;
    for (int ci = 0; ci < CCH; ++ci) {
        const float* xb = x + (size_t)(n * CCH + ci) * HW * HW;
        const float* wb = w + (size_t)(co * CCH + ci) * 9;
#pragma unroll
        for (int u = 0; u < 3; ++u) {
            int yr = 2 * oh + u;
#pragma unroll
            for (int v = 0; v < 3; ++v) {
                int yc = 2 * ow + v;
                float s = 0.f;
#pragma unroll
                for (int a = 0; a < 4; ++a) {
                    int xrw = yr - 2 + a;
                    if (xrw < 0 || xrw >= HW) continue;
                    float t = 0.f;
#pragma unroll
                    for (int b = 0; b < 4; ++b) {
                        int xc = yc - 2 + b;
                        if (xc >= 0 && xc < HW) t += fv[b] * xb[xrw * HW + xc];
                    }
                    s += fv[a] * t;
                }
                acc += wb[u * 3 + v] * s;
            }
        }
    }
    out[idx] = acc;
}

extern "C" void kernel_launch(void* const* d_in, const int* in_sizes, int n_in,
                              void* d_out, int out_size, void* d_ws, size_t ws_size,
                              hipStream_t stream) {
    const float* x = (const float*)d_in[0];
    const float* w = (const float*)d_in[1];
    const float* fk = (const float*)d_in[2];
    float* out = (float*)d_out;

    const size_t ybytes = (size_t)NI * 40 * HY2 * 8 * 2;      // 43,264,000
    const size_t wtoff = ybytes;
    const size_t need = wtoff + (size_t)9 * CCH * CCH * 2;    // 45,107,200

    if (ws_size >= need) {
        __hip_bfloat16* yt = (__hip_bfloat16*)d_ws;
        __hip_bfloat16* wt = (__hip_bfloat16*)((char*)d_ws + wtoff);
        fir_kernel<<<16 * 9 * 20, 256, 0, stream>>>(x, fk, yt);
        wt2_kernel<<<(9 * CCH * CCH + 255) / 256, 256, 0, stream>>>(w, wt);
        conv_kernel<<<16 * 5 * 16, 256, 0, stream>>>(yt, wt, out);
    } else {
        naive_kernel<<<(NI * CCH * 32 * 32 + 255) / 256, 256, 0, stream>>>(x, w, fk, out);
    }
}